// Round 5
// baseline (505.768 us; speedup 1.0000x reference)
//
#include <hip/hip_runtime.h>
#include <utility>

#define DEVI __device__ __forceinline__

namespace {

constexpr int T_ = 128;
constexpr int NCH = 96;
constexpr int CT = NCH * T_;          // 12288
constexpr int NJ = 24;
constexpr int ZDIM = 256;
constexpr int PAR[NJ] = {0,0,0,0,1,2,3,4,5,6,7,8,9,9,9,12,13,14,16,17,18,19,20,21};

struct Q  { float w,x,y,z; };
struct V3 { float x,y,z; };

DEVI Q qmul(Q a, Q b){
  return Q{ a.w*b.w - a.x*b.x - a.y*b.y - a.z*b.z,
            a.w*b.x + a.x*b.w + a.y*b.z - a.z*b.y,
            a.w*b.y - a.x*b.z + a.y*b.w + a.z*b.x,
            a.w*b.z + a.x*b.y - a.y*b.x + a.z*b.w };
}
DEVI Q qconj(Q a){ return Q{a.w,-a.x,-a.y,-a.z}; }
DEVI float qn2(Q a){ return a.w*a.w + a.x*a.x + a.y*a.y + a.z*a.z; }
DEVI Q qscale(Q a, float s){ return Q{a.w*s, a.x*s, a.y*s, a.z*s}; }
DEVI Q qadd(Q a, Q b){ return Q{a.w+b.w, a.x+b.x, a.y+b.y, a.z+b.z}; }
DEVI Q qinv(Q a){ return qscale(qconj(a), 1.0f/qn2(a)); }
DEVI V3 qrot(Q g, V3 v){
  Q t = qmul(g, Q{0.f, v.x, v.y, v.z});
  Q y = qmul(t, qconj(g));
  float in = 1.0f/qn2(g);
  return V3{y.x*in, y.y*in, y.z*in};
}
DEVI Q qinv_bwd(Q q, Q g){
  float n  = qn2(q);
  float in = 1.0f/n;
  float d  = g.w*q.w - g.x*q.x - g.y*q.y - g.z*q.z;   // g . conj(q)
  float c  = 2.0f*d*in*in;
  return Q{ g.w*in - q.w*c, -g.x*in - q.x*c, -g.y*in - q.y*c, -g.z*in - q.z*c };
}
DEVI Q qrot_bwd_g(Q g, V3 v, V3 w){
  float in = 1.0f/qn2(g);
  Q u{0.f, v.x, v.y, v.z};
  Q t = qmul(g, u);
  Q y = qmul(t, qconj(g));
  Q G4{0.f, w.x*in, w.y*in, w.z*in};
  Q dt  = qmul(G4, g);
  Q dcg = qmul(qconj(t), G4);
  Q dg  = qconj(dcg);
  dg = qadd(dg, qmul(dt, qconj(u)));
  float wy = w.x*y.x + w.y*y.y + w.z*y.z;
  dg = qadd(dg, qscale(g, -2.0f*wy*in*in));
  return dg;
}

template<typename F, int... Is>
DEVI void sf_impl(F&& f, std::integer_sequence<int, Is...>){
  (f(std::integral_constant<int, Is>{}), ...);
}
template<int N, typename F>
DEVI void static_for(F&& f){ sf_impl(f, std::make_integer_sequence<int, N>{}); }

template<int Jj>
DEVI Q loadQ(const float (&q)[NJ][4]){ return Q{q[Jj][0], q[Jj][1], q[Jj][2], q[Jj][3]}; }
template<int Jj>
DEVI Q localQ(const float (&q)[NJ][4]){
  if constexpr (Jj < 4) return loadQ<Jj>(q);
  else return qmul(qinv(loadQ<PAR[Jj]>(q)), loadQ<Jj>(q));
}
template<int Jj>
DEVI Q grotRec(const float (&q)[NJ][4]){
  if constexpr (Jj == 0) return Q{1.f,0.f,0.f,0.f};
  else return qmul(grotRec<PAR[Jj]>(q), localQ<Jj>(q));
}

// Original chainFwd (monolith path): exports raw scaled quats via q.
template<bool TGT, typename PJ>
DEVI void chainFwd(const float* __restrict__ base, int t,
                   const float* s_std, const float* s_mean, const float* s_off,
                   float (&q)[NJ][4], PJ&& pj)
{
  Q grot[NJ]; V3 gpos[NJ];
  static_for<NJ>([&](auto jc){
    constexpr int j = decltype(jc)::value;
    if constexpr (j == 0) {
      q[0][0]=1.f; q[0][1]=0.f; q[0][2]=0.f; q[0][3]=0.f;
      grot[0] = Q{1.f,0.f,0.f,0.f};
      gpos[0] = V3{0.f,0.f,0.f};
    } else {
      constexpr int P = PAR[j];
      #pragma unroll
      for (int i = 0; i < 4; ++i){
        const int c  = 4*j + i;
        const int oc = TGT ? (8*j + i) : c;
        q[j][i] = base[oc*T_ + t] * s_std[c] + s_mean[c];
      }
      Q qj{q[j][0], q[j][1], q[j][2], q[j][3]};
      Q L;
      if constexpr (j < 4) L = qj;
      else L = qmul(qinv(Q{q[P][0], q[P][1], q[P][2], q[P][3]}), qj);
      Q gP = grot[P];
      grot[j] = qmul(gP, L);
      V3 o{s_off[3*j], s_off[3*j+1], s_off[3*j+2]};
      V3 r = qrot(gP, o);
      gpos[j] = V3{gpos[P].x + r.x, gpos[P].y + r.y, gpos[P].z + r.z};
    }
    pj(jc, gpos[j]);
  });
}

// Split-path chainFwd: q internal, callback gets (jc, gpos, grot).
template<bool TGT, typename PJ>
DEVI void chainFwdG(const float* __restrict__ base, int t,
                    const float* s_std, const float* s_mean, const float* s_off,
                    PJ&& pj)
{
  float q[NJ][4];
  Q grot[NJ]; V3 gpos[NJ];
  static_for<NJ>([&](auto jc){
    constexpr int j = decltype(jc)::value;
    if constexpr (j == 0) {
      q[0][0]=1.f; q[0][1]=0.f; q[0][2]=0.f; q[0][3]=0.f;
      grot[0] = Q{1.f,0.f,0.f,0.f};
      gpos[0] = V3{0.f,0.f,0.f};
    } else {
      constexpr int P = PAR[j];
      #pragma unroll
      for (int i = 0; i < 4; ++i){
        const int c  = 4*j + i;
        const int oc = TGT ? (8*j + i) : c;
        q[j][i] = base[oc*T_ + t] * s_std[c] + s_mean[c];
      }
      Q qj{q[j][0], q[j][1], q[j][2], q[j][3]};
      Q L;
      if constexpr (j < 4) L = qj;
      else L = qmul(qinv(Q{q[P][0], q[P][1], q[P][2], q[P][3]}), qj);
      Q gP = grot[P];
      grot[j] = qmul(gP, L);
      V3 o{s_off[3*j], s_off[3*j+1], s_off[3*j+2]};
      V3 r = qrot(gP, o);
      gpos[j] = V3{gpos[P].x + r.x, gpos[P].y + r.y, gpos[P].z + r.z};
    }
    pj(jc, gpos[j], grot[j]);
  });
}

DEVI void chainBwd(const float (&q)[NJ][4], const float* s_std, const float* s_off,
                   V3 (&dgp)[NJ], float* __restrict__ Gp, int t)
{
  Q dgr[NJ] = {};
  Q dq [NJ] = {};
  static_for<NJ-1>([&](auto ic){
    constexpr int j = NJ - 1 - decltype(ic)::value;   // 23..1
    constexpr int P = PAR[j];
    V3 w = dgp[j];
    Q gP = grotRec<P>(q);
    if constexpr (P != 0) {
      dgp[P].x += w.x; dgp[P].y += w.y; dgp[P].z += w.z;
      V3 o{s_off[3*j], s_off[3*j+1], s_off[3*j+2]};
      dgr[P] = qadd(dgr[P], qrot_bwd_g(gP, o, w));
    }
    Q Gj = dgr[j];
    Q dL = qmul(qconj(gP), Gj);
    if constexpr (P != 0) {
      dgr[P] = qadd(dgr[P], qmul(Gj, qconj(localQ<j>(q))));
    }
    if constexpr (j < 4) {
      dq[j] = qadd(dq[j], dL);
    } else {
      Q qP  = loadQ<P>(q);
      Q iqP = qinv(qP);
      dq[j] = qadd(dq[j], qmul(qconj(iqP), dL));
      Q dInv = qmul(dL, qconj(loadQ<j>(q)));
      dq[P] = qadd(dq[P], qinv_bwd(qP, dInv));
    }
    Gp[(4*j+0)*T_ + t] = dq[j].w * s_std[4*j+0];
    Gp[(4*j+1)*T_ + t] = dq[j].x * s_std[4*j+1];
    Gp[(4*j+2)*T_ + t] = dq[j].y * s_std[4*j+2];
    Gp[(4*j+3)*T_ + t] = dq[j].z * s_std[4*j+3];
  });
  #pragma unroll
  for (int i = 0; i < 4; ++i) Gp[i*T_ + t] = 0.f;
}

DEVI float waveSum(float v){
  #pragma unroll
  for (int o = 32; o > 0; o >>= 1) v += __shfl_down(v, o);
  return v;
}

} // namespace

// ---------------- kernels ----------------

// qs = base_motion + lat @ W_dec : M=1024, N=12288, K=256
__global__ __launch_bounds__(256) void k_decode(
    const float* __restrict__ base, const float* __restrict__ lat,
    const float* __restrict__ W, float* __restrict__ qs)
{
  __shared__ float As[32][132];
  __shared__ float Bs[32][128];
  const int tid = threadIdx.x;
  const int bn = blockIdx.x * 128;
  const int bm = blockIdx.y * 128;
  float acc[8][8] = {};
  for (int k0 = 0; k0 < 256; k0 += 32) {
    #pragma unroll
    for (int r = 0; r < 4; ++r) {
      int idx = r*256 + tid;
      int row = idx >> 3;
      int kc  = (idx & 7) << 2;
      float4 v = *(const float4*)&lat[(size_t)(bm + row)*256 + k0 + kc];
      As[kc+0][row] = v.x; As[kc+1][row] = v.y;
      As[kc+2][row] = v.z; As[kc+3][row] = v.w;
    }
    #pragma unroll
    for (int r = 0; r < 4; ++r) {
      int idx = r*256 + tid;
      int kr = idx >> 5;
      int nc = (idx & 31) << 2;
      *(float4*)&Bs[kr][nc] = *(const float4*)&W[(size_t)(k0 + kr)*CT + bn + nc];
    }
    __syncthreads();
    const int tx = tid & 15, ty = tid >> 4;
    #pragma unroll
    for (int kk = 0; kk < 32; ++kk) {
      float a[8], b[8];
      float4 a0 = *(float4*)&As[kk][ty*8];
      float4 a1 = *(float4*)&As[kk][ty*8+4];
      float4 b0 = *(float4*)&Bs[kk][tx*8];
      float4 b1 = *(float4*)&Bs[kk][tx*8+4];
      a[0]=a0.x;a[1]=a0.y;a[2]=a0.z;a[3]=a0.w;a[4]=a1.x;a[5]=a1.y;a[6]=a1.z;a[7]=a1.w;
      b[0]=b0.x;b[1]=b0.y;b[2]=b0.z;b[3]=b0.w;b[4]=b1.x;b[5]=b1.y;b[6]=b1.z;b[7]=b1.w;
      #pragma unroll
      for (int i = 0; i < 8; ++i)
        #pragma unroll
        for (int j = 0; j < 8; ++j) acc[i][j] += a[i]*b[j];
    }
    __syncthreads();
  }
  const int tx = tid & 15, ty = tid >> 4;
  #pragma unroll
  for (int i = 0; i < 8; ++i) {
    size_t row = bm + ty*8 + i;
    #pragma unroll
    for (int j = 0; j < 8; j += 4) {
      size_t col = bn + tx*8 + j;
      float4 bv = *(const float4*)&base[row*CT + col];
      float4 o;
      o.x = bv.x + acc[i][j+0]; o.y = bv.y + acc[i][j+1];
      o.z = bv.z + acc[i][j+2]; o.w = bv.w + acc[i][j+3];
      *(float4*)&qs[row*CT + col] = o;
    }
  }
}

// ---- Monolithic k_pose (fallback when ws is small; proven) ----
__global__ __launch_bounds__(128, 1) void k_pose(
    const float* __restrict__ qs,   const float* __restrict__ tmot,
    const float* __restrict__ meanq,const float* __restrict__ stdq,
    const float* __restrict__ offs, float* __restrict__ G,
    float* __restrict__ bpose)
{
  __shared__ float s_std[96], s_mean[96], s_off[72];
  __shared__ float sred[3][2];
  const int p = blockIdx.x;
  const int t = threadIdx.x;
  if (t < 96) { s_std[t] = stdq[t]; s_mean[t] = meanq[t]; }
  if (t < 72) s_off[t] = offs[p*72 + t];
  __syncthreads();

  const float* qs0 = qs   + (size_t)(2*p) * CT;
  const float* qs1 = qs0  + CT;
  const float* tm0 = tmot + (size_t)(2*p) * (2*CT);
  const float* tm1 = tm0  + 2*CT;

  float accR = 0.f, accJ = 0.f;
  #pragma unroll 4
  for (int c = 0; c < 4; ++c) {
    int oc = ((c >> 2) << 3) + (c & 3);
    float d0 = qs0[c*T_ + t] - tm0[oc*T_ + t];
    float d1 = qs1[c*T_ + t] - tm1[oc*T_ + t];
    accR += d0*d0 + d1*d1;
  }
  #pragma unroll 4
  for (int c = 4; c < 96; ++c) {
    int oc = ((c >> 2) << 3) + (c & 3);
    float d0 = qs0[c*T_ + t] - tm0[oc*T_ + t];
    float d1 = qs1[c*T_ + t] - tm1[oc*T_ + t];
    accJ += d0*d0 + d1*d1;
  }

  float fkAcc = 0.f;
  V3 posA[NJ], posB[NJ];
  float qtmp[NJ][4], qd0[NJ][4];

  chainFwd<true >(tm0, t, s_std, s_mean, s_off, qtmp,
    [&](auto jc, V3 g){ posA[decltype(jc)::value] = g; });
  chainFwd<false>(qs0, t, s_std, s_mean, s_off, qd0,
    [&](auto jc, V3 g){
      constexpr int j = decltype(jc)::value;
      float dx = g.x - posA[j].x, dy = g.y - posA[j].y, dz = g.z - posA[j].z;
      fkAcc += dx*dx + dy*dy + dz*dz;
      posB[j] = g;
    });
  chainFwd<true >(tm1, t, s_std, s_mean, s_off, qtmp,
    [&](auto jc, V3 g){ posA[decltype(jc)::value] = g; });
  V3 dgp[NJ];
  chainFwd<false>(qs1, t, s_std, s_mean, s_off, qtmp,
    [&](auto jc, V3 g){
      constexpr int j = decltype(jc)::value;
      float dx = g.x - posA[j].x, dy = g.y - posA[j].y, dz = g.z - posA[j].z;
      fkAcc += dx*dx + dy*dy + dz*dz;
      dgp[j] = V3{2.f*(posB[j].x - g.x), 2.f*(posB[j].y - g.y), 2.f*(posB[j].z - g.z)};
    });

  chainBwd(qd0, s_std, s_off, dgp, G + (size_t)p * CT, t);

  float r  = waveSum(accR);
  float jj = waveSum(accJ);
  float fk = waveSum(fkAcc);
  const int wid = t >> 6;
  if ((t & 63) == 0) { sred[0][wid] = r; sred[1][wid] = jj; sred[2][wid] = fk; }
  __syncthreads();
  if (t == 0) {
    bpose[p]        = sred[0][0] + sred[0][1];
    bpose[512 + p]  = sred[1][0] + sred[1][1];
    bpose[1024 + p] = sred[2][0] + sred[2][1];
  }
}

// ---- Split path: fwd (losses + chains, stream grot/dgp) ----
__global__ __launch_bounds__(128) void k_pose_fwd(
    const float* __restrict__ qs,   const float* __restrict__ tmot,
    const float* __restrict__ meanq,const float* __restrict__ stdq,
    const float* __restrict__ offs, float* __restrict__ grot_ws,
    float* __restrict__ dgp_ws,     float* __restrict__ bpose)
{
  __shared__ float s_std[96], s_mean[96], s_off[72];
  __shared__ float sred[3][2];
  const int p = blockIdx.x;
  const int t = threadIdx.x;
  if (t < 96) { s_std[t] = stdq[t]; s_mean[t] = meanq[t]; }
  if (t < 72) s_off[t] = offs[p*72 + t];
  __syncthreads();

  const float* qs0 = qs   + (size_t)(2*p) * CT;
  const float* qs1 = qs0  + CT;
  const float* tm0 = tmot + (size_t)(2*p) * (2*CT);
  const float* tm1 = tm0  + 2*CT;

  float accR = 0.f, accJ = 0.f;
  #pragma unroll 4
  for (int c = 0; c < 4; ++c) {
    int oc = ((c >> 2) << 3) + (c & 3);
    float d0 = qs0[c*T_ + t] - tm0[oc*T_ + t];
    float d1 = qs1[c*T_ + t] - tm1[oc*T_ + t];
    accR += d0*d0 + d1*d1;
  }
  #pragma unroll 4
  for (int c = 4; c < 96; ++c) {
    int oc = ((c >> 2) << 3) + (c & 3);
    float d0 = qs0[c*T_ + t] - tm0[oc*T_ + t];
    float d1 = qs1[c*T_ + t] - tm1[oc*T_ + t];
    accJ += d0*d0 + d1*d1;
  }

  float fkAcc = 0.f;
  V3 posA[NJ], posB[NJ];
  float* gw = grot_ws + (size_t)p * (NJ*4*T_);
  float* dw = dgp_ws  + (size_t)p * (NJ*3*T_);

  chainFwdG<true >(tm0, t, s_std, s_mean, s_off,
    [&](auto jc, V3 g, Q gr){ posA[decltype(jc)::value] = g; (void)gr; });
  chainFwdG<false>(qs0, t, s_std, s_mean, s_off,
    [&](auto jc, V3 g, Q gr){
      constexpr int j = decltype(jc)::value;
      float dx = g.x - posA[j].x, dy = g.y - posA[j].y, dz = g.z - posA[j].z;
      fkAcc += dx*dx + dy*dy + dz*dz;
      posB[j] = g;
      if constexpr (j >= 1) {
        gw[(j*4+0)*T_ + t] = gr.w; gw[(j*4+1)*T_ + t] = gr.x;
        gw[(j*4+2)*T_ + t] = gr.y; gw[(j*4+3)*T_ + t] = gr.z;
      }
    });
  chainFwdG<true >(tm1, t, s_std, s_mean, s_off,
    [&](auto jc, V3 g, Q gr){ posA[decltype(jc)::value] = g; (void)gr; });
  chainFwdG<false>(qs1, t, s_std, s_mean, s_off,
    [&](auto jc, V3 g, Q gr){
      constexpr int j = decltype(jc)::value;
      float dx = g.x - posA[j].x, dy = g.y - posA[j].y, dz = g.z - posA[j].z;
      fkAcc += dx*dx + dy*dy + dz*dz;
      (void)gr;
      if constexpr (j >= 1) {
        dw[(j*3+0)*T_ + t] = 2.f*(posB[j].x - g.x);
        dw[(j*3+1)*T_ + t] = 2.f*(posB[j].y - g.y);
        dw[(j*3+2)*T_ + t] = 2.f*(posB[j].z - g.z);
      }
    });

  float r  = waveSum(accR);
  float jj = waveSum(accJ);
  float fk = waveSum(fkAcc);
  const int wid = t >> 6;
  if ((t & 63) == 0) { sred[0][wid] = r; sred[1][wid] = jj; sred[2][wid] = fk; }
  __syncthreads();
  if (t == 0) {
    bpose[p]        = sred[0][0] + sred[0][1];
    bpose[512 + p]  = sred[1][0] + sred[1][1];
    bpose[1024 + p] = sred[2][0] + sred[2][1];
  }
}

// ---- Split path: bwd (grot/dgp from ws, write G) ----
__global__ __launch_bounds__(128) void k_pose_bwd(
    const float* __restrict__ qs,   const float* __restrict__ meanq,
    const float* __restrict__ stdq, const float* __restrict__ offs,
    const float* __restrict__ grot_ws, const float* __restrict__ dgp_ws,
    float* __restrict__ G)
{
  __shared__ float s_std[96], s_mean[96], s_off[72];
  const int p = blockIdx.x;
  const int t = threadIdx.x;
  if (t < 96) { s_std[t] = stdq[t]; s_mean[t] = meanq[t]; }
  if (t < 72) s_off[t] = offs[p*72 + t];
  __syncthreads();

  const float* qs0 = qs + (size_t)(2*p) * CT;
  const float* gw  = grot_ws + (size_t)p * (NJ*4*T_);
  const float* dw  = dgp_ws  + (size_t)p * (NJ*3*T_);
  float* Gp = G + (size_t)p * CT;

  float q[NJ][4];
  q[0][0]=1.f; q[0][1]=0.f; q[0][2]=0.f; q[0][3]=0.f;
  static_for<NJ-1>([&](auto jc){
    constexpr int j = decltype(jc)::value + 1;      // 1..23
    #pragma unroll
    for (int i = 0; i < 4; ++i) {
      const int c = 4*j + i;
      q[j][i] = qs0[c*T_ + t] * s_std[c] + s_mean[c];
    }
  });

  V3 dgpacc[NJ] = {};
  Q dgr[NJ] = {};
  Q dq [NJ] = {};
  static_for<NJ-1>([&](auto ic){
    constexpr int j = NJ - 1 - decltype(ic)::value;   // 23..1
    constexpr int P = PAR[j];
    V3 w{ dw[(j*3+0)*T_ + t] + dgpacc[j].x,
          dw[(j*3+1)*T_ + t] + dgpacc[j].y,
          dw[(j*3+2)*T_ + t] + dgpacc[j].z };
    Q gP;
    if constexpr (P == 0) gP = Q{1.f,0.f,0.f,0.f};
    else gP = Q{ gw[(P*4+0)*T_ + t], gw[(P*4+1)*T_ + t],
                 gw[(P*4+2)*T_ + t], gw[(P*4+3)*T_ + t] };
    if constexpr (P != 0) {
      dgpacc[P].x += w.x; dgpacc[P].y += w.y; dgpacc[P].z += w.z;
      V3 o{s_off[3*j], s_off[3*j+1], s_off[3*j+2]};
      dgr[P] = qadd(dgr[P], qrot_bwd_g(gP, o, w));
    }
    Q Gj = dgr[j];
    Q dL = qmul(qconj(gP), Gj);
    if constexpr (P != 0) {
      Q localj = qmul(qinv(loadQ<P>(q)), loadQ<j>(q));
      dgr[P] = qadd(dgr[P], qmul(Gj, qconj(localj)));
    }
    if constexpr (j < 4) {
      dq[j] = qadd(dq[j], dL);
    } else {
      Q qP  = loadQ<P>(q);
      Q iqP = qinv(qP);
      dq[j] = qadd(dq[j], qmul(qconj(iqP), dL));
      Q dInv = qmul(dL, qconj(loadQ<j>(q)));
      dq[P] = qadd(dq[P], qinv_bwd(qP, dInv));
    }
    Gp[(4*j+0)*T_ + t] = dq[j].w * s_std[4*j+0];
    Gp[(4*j+1)*T_ + t] = dq[j].x * s_std[4*j+1];
    Gp[(4*j+2)*T_ + t] = dq[j].y * s_std[4*j+2];
    Gp[(4*j+3)*T_ + t] = dq[j].z * s_std[4*j+3];
  });
  #pragma unroll
  for (int i = 0; i < 4; ++i) Gp[i*T_ + t] = 0.f;
}

// grad partials: part[s][p][z], SPLITK=16, K-chunk 768 (256 blocks)
__global__ __launch_bounds__(256) void k_gradgemm(
    const float* __restrict__ G, const float* __restrict__ W,
    float* __restrict__ part)
{
  __shared__ float As[64][33];
  __shared__ float Bs[128][33];
  const int tid = threadIdx.x;
  const int bn = blockIdx.x * 128;
  const int bm = blockIdx.y * 64;
  const int s  = blockIdx.z;
  const int kb = s * 768;
  float acc[4][8] = {};
  for (int k0 = 0; k0 < 768; k0 += 32) {
    #pragma unroll
    for (int r = 0; r < 2; ++r) {
      int idx = r*256 + tid;
      int row = idx >> 3;
      int kc  = (idx & 7) << 2;
      float4 v = *(const float4*)&G[(size_t)(bm + row)*CT + kb + k0 + kc];
      As[row][kc+0]=v.x; As[row][kc+1]=v.y; As[row][kc+2]=v.z; As[row][kc+3]=v.w;
    }
    #pragma unroll
    for (int r = 0; r < 4; ++r) {
      int idx = r*256 + tid;
      int row = idx >> 3;
      int kc  = (idx & 7) << 2;
      float4 v = *(const float4*)&W[(size_t)(bn + row)*CT + kb + k0 + kc];
      Bs[row][kc+0]=v.x; Bs[row][kc+1]=v.y; Bs[row][kc+2]=v.z; Bs[row][kc+3]=v.w;
    }
    __syncthreads();
    const int tx = tid & 15, ty = tid >> 4;
    #pragma unroll
    for (int kk = 0; kk < 32; ++kk) {
      float a[4], b[8];
      #pragma unroll
      for (int i = 0; i < 4; ++i) a[i] = As[ty*4+i][kk];
      #pragma unroll
      for (int j = 0; j < 8; ++j) b[j] = Bs[tx*8+j][kk];
      #pragma unroll
      for (int i = 0; i < 4; ++i)
        #pragma unroll
        for (int j = 0; j < 8; ++j) acc[i][j] += a[i]*b[j];
    }
    __syncthreads();
  }
  const int tx = tid & 15, ty = tid >> 4;
  #pragma unroll
  for (int i = 0; i < 4; ++i) {
    size_t pr = (size_t)s*131072 + (size_t)(bm + ty*4 + i)*256 + bn + tx*8;
    float4 o0{acc[i][0], acc[i][1], acc[i][2], acc[i][3]};
    float4 o1{acc[i][4], acc[i][5], acc[i][6], acc[i][7]};
    *(float4*)&part[pr]   = o0;
    *(float4*)&part[pr+4] = o1;
  }
}

// disp / kld / cons reductions — float4, block-partial, no atomics
__global__ __launch_bounds__(256) void k_rest(
    const float* __restrict__ ind, const float* __restrict__ tgd,
    const float* __restrict__ mu,  const float* __restrict__ lv,
    const float* __restrict__ lat, const float* __restrict__ part,
    float* __restrict__ brest)
{
  __shared__ float sred[3][4];
  const int t = threadIdx.x;
  const int gid = blockIdx.x * 256 + t;            // 0..131071
  float a0 = 0.f, a1 = 0.f, a2 = 0.f;
  if (gid < 98304) {
    float4 a = ((const float4*)ind)[gid];
    float4 b = ((const float4*)tgd)[gid];
    float dx=a.x-b.x, dy=a.y-b.y, dz=a.z-b.z, dw=a.w-b.w;
    a0 = dx*dx + dy*dy + dz*dz + dw*dw;
  }
  if (gid < 65536) {
    float4 l = ((const float4*)lv)[gid];
    float4 m = ((const float4*)mu)[gid];
    a1 = (1.f + l.x - m.x*m.x - __expf(l.x)) + (1.f + l.y - m.y*m.y - __expf(l.y))
       + (1.f + l.z - m.z*m.z - __expf(l.z)) + (1.f + l.w - m.w*m.w - __expf(l.w));
  }
  if (gid < 32768) {
    float4 g{0.f,0.f,0.f,0.f};
    #pragma unroll
    for (int s = 0; s < 16; ++s) {
      float4 v = ((const float4*)(part + (size_t)s*131072))[gid];
      g.x += v.x; g.y += v.y; g.z += v.z; g.w += v.w;
    }
    int p  = gid >> 6;
    int zb = (gid & 63) << 2;
    float4 La = *(const float4*)&lat[(size_t)(2*p)*ZDIM + zb];
    float4 Lb = *(const float4*)&lat[(size_t)(2*p+1)*ZDIM + zb];
    float vx = La.x - g.x - Lb.x, vy = La.y - g.y - Lb.y;
    float vz = La.z - g.z - Lb.z, vw = La.w - g.w - Lb.w;
    a2 = vx*vx + vy*vy + vz*vz + vw*vw;
  }
  a0 = waveSum(a0); a1 = waveSum(a1); a2 = waveSum(a2);
  const int wid = t >> 6;
  if ((t & 63) == 0) { sred[0][wid]=a0; sred[1][wid]=a1; sred[2][wid]=a2; }
  __syncthreads();
  if (t == 0) {
    brest[blockIdx.x]        = sred[0][0]+sred[0][1]+sred[0][2]+sred[0][3];
    brest[512 + blockIdx.x]  = sred[1][0]+sred[1][1]+sred[1][2]+sred[1][3];
    brest[1024 + blockIdx.x] = sred[2][0]+sred[2][1]+sred[2][2]+sred[2][3];
  }
}

__global__ __launch_bounds__(256) void k_final(
    const float* __restrict__ bpose, const float* __restrict__ brest,
    float* __restrict__ out)
{
  __shared__ float sred[4];
  const int t = threadIdx.x;
  float tot[6];
  const float* srcs[6] = { bpose, bpose+512, bpose+1024, brest, brest+512, brest+1024 };
  #pragma unroll
  for (int c = 0; c < 6; ++c) {
    float x = srcs[c][t] + srcs[c][t+256];
    x = waveSum(x);
    if ((t & 63) == 0) sred[t>>6] = x;
    __syncthreads();
    tot[c] = sred[0]+sred[1]+sred[2]+sred[3];
    __syncthreads();
  }
  if (t == 0) {
    out[0] = 0.001f * (-0.5f * tot[4] * (1.f/1024.f));       // kld
    out[1] = tot[0] * (1.f/524288.f);                        // root
    out[2] = tot[3] * (1.f/393216.f);                        // disp
    out[3] = 0.1f * (tot[5] * (1.f/131072.f));               // cons
    out[4] = 0.1f * (tot[2] * (1.f/9437184.f));              // fk
    out[5] = tot[1] * (1.f/12058624.f);                      // joints
  }
}

extern "C" void kernel_launch(void* const* d_in, const int* in_sizes, int n_in,
                              void* d_out, int out_size, void* d_ws, size_t ws_size,
                              hipStream_t stream)
{
  (void)in_sizes; (void)n_in; (void)out_size;
  const float* base = (const float*)d_in[0];
  const float* tmot = (const float*)d_in[1];
  const float* ind  = (const float*)d_in[2];
  const float* tgd  = (const float*)d_in[3];
  const float* mu   = (const float*)d_in[4];
  const float* lv   = (const float*)d_in[5];
  const float* lat  = (const float*)d_in[6];
  const float* W    = (const float*)d_in[7];
  const float* meanq= (const float*)d_in[8];
  const float* stdq = (const float*)d_in[9];
  const float* offs = (const float*)d_in[10];
  float* out = (float*)d_out;

  char* ws = (char*)d_ws;
  float* qs = (float*)(ws);                          // 50,331,648 B
  float* G  = (float*)(ws + 50331648);               // 25,165,824 B

  // split-mode extras (grot dead before part is produced -> part aliases grot)
  constexpr size_t OFF_GROT = 75497472;              // 25,165,824 B
  constexpr size_t OFF_PART_SPLIT = 75497472;        //  8,388,608 B (alias)
  constexpr size_t OFF_DGP  = 100663296;             // 18,874,368 B
  constexpr size_t OFF_BPOSE_SPLIT = 119537664;      // 6,144 B
  constexpr size_t OFF_BREST_SPLIT = 119543808;      // 6,144 B
  constexpr size_t WS_SPLIT_NEED   = 119549952;

  hipLaunchKernelGGL(k_decode, dim3(96, 8), dim3(256), 0, stream, base, lat, W, qs);

  if (ws_size >= WS_SPLIT_NEED) {
    float* grot  = (float*)(ws + OFF_GROT);
    float* dgp   = (float*)(ws + OFF_DGP);
    float* part  = (float*)(ws + OFF_PART_SPLIT);
    float* bpose = (float*)(ws + OFF_BPOSE_SPLIT);
    float* brest = (float*)(ws + OFF_BREST_SPLIT);
    hipLaunchKernelGGL(k_pose_fwd, dim3(512), dim3(128), 0, stream,
                       qs, tmot, meanq, stdq, offs, grot, dgp, bpose);
    hipLaunchKernelGGL(k_pose_bwd, dim3(512), dim3(128), 0, stream,
                       qs, meanq, stdq, offs, grot, dgp, G);
    hipLaunchKernelGGL(k_gradgemm, dim3(2, 8, 16), dim3(256), 0, stream, G, W, part);
    hipLaunchKernelGGL(k_rest, dim3(512), dim3(256), 0, stream,
                       ind, tgd, mu, lv, lat, part, brest);
    hipLaunchKernelGGL(k_final, dim3(1), dim3(256), 0, stream, bpose, brest, out);
  } else {
    float* part  = (float*)(ws + 75497472);          // 16*512*256*4 = 8,388,608
    float* bpose = (float*)(ws + 83886080);
    float* brest = (float*)(ws + 83892224);
    hipLaunchKernelGGL(k_pose, dim3(512), dim3(128), 0, stream,
                       qs, tmot, meanq, stdq, offs, G, bpose);
    hipLaunchKernelGGL(k_gradgemm, dim3(2, 8, 16), dim3(256), 0, stream, G, W, part);
    hipLaunchKernelGGL(k_rest, dim3(512), dim3(256), 0, stream,
                       ind, tgd, mu, lv, lat, part, brest);
    hipLaunchKernelGGL(k_final, dim3(1), dim3(256), 0, stream, bpose, brest, out);
  }
}

// Round 6
// 423.460 us; speedup vs baseline: 1.1944x; 1.1944x over previous
//
#include <hip/hip_runtime.h>
#include <utility>

#define DEVI __device__ __forceinline__

namespace {

constexpr int T_ = 128;
constexpr int NCH = 96;
constexpr int CT = NCH * T_;          // 12288
constexpr int NJ = 24;
constexpr int ZDIM = 256;
constexpr int PAR[NJ] = {0,0,0,0,1,2,3,4,5,6,7,8,9,9,9,12,13,14,16,17,18,19,20,21};

struct Q  { float w,x,y,z; };
struct V3 { float x,y,z; };

DEVI Q qmul(Q a, Q b){
  return Q{ a.w*b.w - a.x*b.x - a.y*b.y - a.z*b.z,
            a.w*b.x + a.x*b.w + a.y*b.z - a.z*b.y,
            a.w*b.y - a.x*b.z + a.y*b.w + a.z*b.x,
            a.w*b.z + a.x*b.y - a.y*b.x + a.z*b.w };
}
DEVI Q qconj(Q a){ return Q{a.w,-a.x,-a.y,-a.z}; }
DEVI float qn2(Q a){ return a.w*a.w + a.x*a.x + a.y*a.y + a.z*a.z; }
DEVI Q qscale(Q a, float s){ return Q{a.w*s, a.x*s, a.y*s, a.z*s}; }
DEVI Q qadd(Q a, Q b){ return Q{a.w+b.w, a.x+b.x, a.y+b.y, a.z+b.z}; }
DEVI Q qinv(Q a){ return qscale(qconj(a), 1.0f/qn2(a)); }
DEVI V3 qrot(Q g, V3 v){
  Q t = qmul(g, Q{0.f, v.x, v.y, v.z});
  Q y = qmul(t, qconj(g));
  float in = 1.0f/qn2(g);
  return V3{y.x*in, y.y*in, y.z*in};
}
DEVI Q qinv_bwd(Q q, Q g){
  float n  = qn2(q);
  float in = 1.0f/n;
  float d  = g.w*q.w - g.x*q.x - g.y*q.y - g.z*q.z;   // g . conj(q)
  float c  = 2.0f*d*in*in;
  return Q{ g.w*in - q.w*c, -g.x*in - q.x*c, -g.y*in - q.y*c, -g.z*in - q.z*c };
}
DEVI Q qrot_bwd_g(Q g, V3 v, V3 w){
  float in = 1.0f/qn2(g);
  Q u{0.f, v.x, v.y, v.z};
  Q t = qmul(g, u);
  Q y = qmul(t, qconj(g));
  Q G4{0.f, w.x*in, w.y*in, w.z*in};
  Q dt  = qmul(G4, g);
  Q dcg = qmul(qconj(t), G4);
  Q dg  = qconj(dcg);
  dg = qadd(dg, qmul(dt, qconj(u)));
  float wy = w.x*y.x + w.y*y.y + w.z*y.z;
  dg = qadd(dg, qscale(g, -2.0f*wy*in*in));
  return dg;
}

template<typename F, int... Is>
DEVI void sf_impl(F&& f, std::integer_sequence<int, Is...>){
  (f(std::integral_constant<int, Is>{}), ...);
}
template<int N, typename F>
DEVI void static_for(F&& f){ sf_impl(f, std::make_integer_sequence<int, N>{}); }

template<int Jj>
DEVI Q loadQ(const float (&q)[NJ][4]){ return Q{q[Jj][0], q[Jj][1], q[Jj][2], q[Jj][3]}; }
template<int Jj>
DEVI Q localQ(const float (&q)[NJ][4]){
  if constexpr (Jj < 4) return loadQ<Jj>(q);
  else return qmul(qinv(loadQ<PAR[Jj]>(q)), loadQ<Jj>(q));
}
template<int Jj>
DEVI Q grotRec(const float (&q)[NJ][4]){
  if constexpr (Jj == 0) return Q{1.f,0.f,0.f,0.f};
  else return qmul(grotRec<PAR[Jj]>(q), localQ<Jj>(q));
}

// Monolith-path chainFwd (fallback kernel only).
template<bool TGT, typename PJ>
DEVI void chainFwd(const float* __restrict__ base, int t,
                   const float* s_std, const float* s_mean, const float* s_off,
                   float (&q)[NJ][4], PJ&& pj)
{
  Q grot[NJ]; V3 gpos[NJ];
  static_for<NJ>([&](auto jc){
    constexpr int j = decltype(jc)::value;
    if constexpr (j == 0) {
      q[0][0]=1.f; q[0][1]=0.f; q[0][2]=0.f; q[0][3]=0.f;
      grot[0] = Q{1.f,0.f,0.f,0.f};
      gpos[0] = V3{0.f,0.f,0.f};
    } else {
      constexpr int P = PAR[j];
      #pragma unroll
      for (int i = 0; i < 4; ++i){
        const int c  = 4*j + i;
        const int oc = TGT ? (8*j + i) : c;
        q[j][i] = base[oc*T_ + t] * s_std[c] + s_mean[c];
      }
      Q qj{q[j][0], q[j][1], q[j][2], q[j][3]};
      Q L;
      if constexpr (j < 4) L = qj;
      else L = qmul(qinv(Q{q[P][0], q[P][1], q[P][2], q[P][3]}), qj);
      Q gP = grot[P];
      grot[j] = qmul(gP, L);
      V3 o{s_off[3*j], s_off[3*j+1], s_off[3*j+2]};
      V3 r = qrot(gP, o);
      gpos[j] = V3{gpos[P].x + r.x, gpos[P].y + r.y, gpos[P].z + r.z};
    }
    pj(jc, gpos[j]);
  });
}

// One FK step for one chain (frontier-live arrays, constexpr indexed).
template<int J>
DEVI void stepChain(Q (&q)[NJ], Q (&g)[NJ], V3 (&pos)[NJ], Q qj, const float* s_off)
{
  constexpr int P = PAR[J];
  Q L;
  if constexpr (J < 4) L = qj;
  else L = qmul(qinv(q[P]), qj);
  q[J] = qj;
  g[J] = qmul(g[P], L);
  V3 o{s_off[3*J], s_off[3*J+1], s_off[3*J+2]};
  V3 r = qrot(g[P], o);
  pos[J] = V3{pos[P].x + r.x, pos[P].y + r.y, pos[P].z + r.z};
}

DEVI void chainBwd(const float (&q)[NJ][4], const float* s_std, const float* s_off,
                   V3 (&dgp)[NJ], float* __restrict__ Gp, int t)
{
  Q dgr[NJ] = {};
  Q dq [NJ] = {};
  static_for<NJ-1>([&](auto ic){
    constexpr int j = NJ - 1 - decltype(ic)::value;   // 23..1
    constexpr int P = PAR[j];
    V3 w = dgp[j];
    Q gP = grotRec<P>(q);
    if constexpr (P != 0) {
      dgp[P].x += w.x; dgp[P].y += w.y; dgp[P].z += w.z;
      V3 o{s_off[3*j], s_off[3*j+1], s_off[3*j+2]};
      dgr[P] = qadd(dgr[P], qrot_bwd_g(gP, o, w));
    }
    Q Gj = dgr[j];
    Q dL = qmul(qconj(gP), Gj);
    if constexpr (P != 0) {
      dgr[P] = qadd(dgr[P], qmul(Gj, qconj(localQ<j>(q))));
    }
    if constexpr (j < 4) {
      dq[j] = qadd(dq[j], dL);
    } else {
      Q qP  = loadQ<P>(q);
      Q iqP = qinv(qP);
      dq[j] = qadd(dq[j], qmul(qconj(iqP), dL));
      Q dInv = qmul(dL, qconj(loadQ<j>(q)));
      dq[P] = qadd(dq[P], qinv_bwd(qP, dInv));
    }
    Gp[(4*j+0)*T_ + t] = dq[j].w * s_std[4*j+0];
    Gp[(4*j+1)*T_ + t] = dq[j].x * s_std[4*j+1];
    Gp[(4*j+2)*T_ + t] = dq[j].y * s_std[4*j+2];
    Gp[(4*j+3)*T_ + t] = dq[j].z * s_std[4*j+3];
  });
  #pragma unroll
  for (int i = 0; i < 4; ++i) Gp[i*T_ + t] = 0.f;
}

DEVI float waveSum(float v){
  #pragma unroll
  for (int o = 32; o > 0; o >>= 1) v += __shfl_down(v, o);
  return v;
}

} // namespace

// ---------------- kernels ----------------

// qs = base_motion + lat @ W_dec : M=1024, N=12288, K=256
__global__ __launch_bounds__(256) void k_decode(
    const float* __restrict__ base, const float* __restrict__ lat,
    const float* __restrict__ W, float* __restrict__ qs)
{
  __shared__ float As[32][132];
  __shared__ float Bs[32][128];
  const int tid = threadIdx.x;
  const int bn = blockIdx.x * 128;
  const int bm = blockIdx.y * 128;
  float acc[8][8] = {};
  for (int k0 = 0; k0 < 256; k0 += 32) {
    #pragma unroll
    for (int r = 0; r < 4; ++r) {
      int idx = r*256 + tid;
      int row = idx >> 3;
      int kc  = (idx & 7) << 2;
      float4 v = *(const float4*)&lat[(size_t)(bm + row)*256 + k0 + kc];
      As[kc+0][row] = v.x; As[kc+1][row] = v.y;
      As[kc+2][row] = v.z; As[kc+3][row] = v.w;
    }
    #pragma unroll
    for (int r = 0; r < 4; ++r) {
      int idx = r*256 + tid;
      int kr = idx >> 5;
      int nc = (idx & 31) << 2;
      *(float4*)&Bs[kr][nc] = *(const float4*)&W[(size_t)(k0 + kr)*CT + bn + nc];
    }
    __syncthreads();
    const int tx = tid & 15, ty = tid >> 4;
    #pragma unroll
    for (int kk = 0; kk < 32; ++kk) {
      float a[8], b[8];
      float4 a0 = *(float4*)&As[kk][ty*8];
      float4 a1 = *(float4*)&As[kk][ty*8+4];
      float4 b0 = *(float4*)&Bs[kk][tx*8];
      float4 b1 = *(float4*)&Bs[kk][tx*8+4];
      a[0]=a0.x;a[1]=a0.y;a[2]=a0.z;a[3]=a0.w;a[4]=a1.x;a[5]=a1.y;a[6]=a1.z;a[7]=a1.w;
      b[0]=b0.x;b[1]=b0.y;b[2]=b0.z;b[3]=b0.w;b[4]=b1.x;b[5]=b1.y;b[6]=b1.z;b[7]=b1.w;
      #pragma unroll
      for (int i = 0; i < 8; ++i)
        #pragma unroll
        for (int j = 0; j < 8; ++j) acc[i][j] += a[i]*b[j];
    }
    __syncthreads();
  }
  const int tx = tid & 15, ty = tid >> 4;
  #pragma unroll
  for (int i = 0; i < 8; ++i) {
    size_t row = bm + ty*8 + i;
    #pragma unroll
    for (int j = 0; j < 8; j += 4) {
      size_t col = bn + tx*8 + j;
      float4 bv = *(const float4*)&base[row*CT + col];
      float4 o;
      o.x = bv.x + acc[i][j+0]; o.y = bv.y + acc[i][j+1];
      o.z = bv.z + acc[i][j+2]; o.w = bv.w + acc[i][j+3];
      *(float4*)&qs[row*CT + col] = o;
    }
  }
}

// ---- Monolithic k_pose (fallback when ws is small; proven) ----
__global__ __launch_bounds__(128, 1) void k_pose(
    const float* __restrict__ qs,   const float* __restrict__ tmot,
    const float* __restrict__ meanq,const float* __restrict__ stdq,
    const float* __restrict__ offs, float* __restrict__ G,
    float* __restrict__ bpose)
{
  __shared__ float s_std[96], s_mean[96], s_off[72];
  __shared__ float sred[3][2];
  const int p = blockIdx.x;
  const int t = threadIdx.x;
  if (t < 96) { s_std[t] = stdq[t]; s_mean[t] = meanq[t]; }
  if (t < 72) s_off[t] = offs[p*72 + t];
  __syncthreads();

  const float* qs0 = qs   + (size_t)(2*p) * CT;
  const float* qs1 = qs0  + CT;
  const float* tm0 = tmot + (size_t)(2*p) * (2*CT);
  const float* tm1 = tm0  + 2*CT;

  float accR = 0.f, accJ = 0.f;
  #pragma unroll 4
  for (int c = 0; c < 4; ++c) {
    int oc = ((c >> 2) << 3) + (c & 3);
    float d0 = qs0[c*T_ + t] - tm0[oc*T_ + t];
    float d1 = qs1[c*T_ + t] - tm1[oc*T_ + t];
    accR += d0*d0 + d1*d1;
  }
  #pragma unroll 4
  for (int c = 4; c < 96; ++c) {
    int oc = ((c >> 2) << 3) + (c & 3);
    float d0 = qs0[c*T_ + t] - tm0[oc*T_ + t];
    float d1 = qs1[c*T_ + t] - tm1[oc*T_ + t];
    accJ += d0*d0 + d1*d1;
  }

  float fkAcc = 0.f;
  V3 posA[NJ], posB[NJ];
  float qtmp[NJ][4], qd0[NJ][4];

  chainFwd<true >(tm0, t, s_std, s_mean, s_off, qtmp,
    [&](auto jc, V3 g){ posA[decltype(jc)::value] = g; });
  chainFwd<false>(qs0, t, s_std, s_mean, s_off, qd0,
    [&](auto jc, V3 g){
      constexpr int j = decltype(jc)::value;
      float dx = g.x - posA[j].x, dy = g.y - posA[j].y, dz = g.z - posA[j].z;
      fkAcc += dx*dx + dy*dy + dz*dz;
      posB[j] = g;
    });
  chainFwd<true >(tm1, t, s_std, s_mean, s_off, qtmp,
    [&](auto jc, V3 g){ posA[decltype(jc)::value] = g; });
  V3 dgp[NJ];
  chainFwd<false>(qs1, t, s_std, s_mean, s_off, qtmp,
    [&](auto jc, V3 g){
      constexpr int j = decltype(jc)::value;
      float dx = g.x - posA[j].x, dy = g.y - posA[j].y, dz = g.z - posA[j].z;
      fkAcc += dx*dx + dy*dy + dz*dz;
      dgp[j] = V3{2.f*(posB[j].x - g.x), 2.f*(posB[j].y - g.y), 2.f*(posB[j].z - g.z)};
    });

  chainBwd(qd0, s_std, s_off, dgp, G + (size_t)p * CT, t);

  float r  = waveSum(accR);
  float jj = waveSum(accJ);
  float fk = waveSum(fkAcc);
  const int wid = t >> 6;
  if ((t & 63) == 0) { sred[0][wid] = r; sred[1][wid] = jj; sred[2][wid] = fk; }
  __syncthreads();
  if (t == 0) {
    bpose[p]        = sred[0][0] + sred[0][1];
    bpose[512 + p]  = sred[1][0] + sred[1][1];
    bpose[1024 + p] = sred[2][0] + sred[2][1];
  }
}

// ---- Split path fwd: 4 chains INTERLEAVED joint-by-joint (frontier-live) ----
__global__ __launch_bounds__(128) void k_pose_fwd(
    const float* __restrict__ qs,   const float* __restrict__ tmot,
    const float* __restrict__ meanq,const float* __restrict__ stdq,
    const float* __restrict__ offs, float* __restrict__ grot_ws,
    float* __restrict__ dgp_ws,     float* __restrict__ bpose)
{
  __shared__ float s_std[96], s_mean[96], s_off[72];
  __shared__ float sred[3][2];
  const int p = blockIdx.x;
  const int t = threadIdx.x;
  if (t < 96) { s_std[t] = stdq[t]; s_mean[t] = meanq[t]; }
  if (t < 72) s_off[t] = offs[p*72 + t];
  __syncthreads();

  const float* qs0 = qs   + (size_t)(2*p) * CT;
  const float* qs1 = qs0  + CT;
  const float* tm0 = tmot + (size_t)(2*p) * (2*CT);
  const float* tm1 = tm0  + 2*CT;
  float* gw = grot_ws + (size_t)p * (NJ*4*T_);
  float* dw = dgp_ws  + (size_t)p * (NJ*3*T_);

  float accR = 0.f, accJ = 0.f, fkAcc = 0.f;

  // root-channel loss (raw values)
  #pragma unroll
  for (int c = 0; c < 4; ++c) {
    float d0 = qs0[c*T_ + t] - tm0[c*T_ + t];
    float d1 = qs1[c*T_ + t] - tm1[c*T_ + t];
    accR += d0*d0 + d1*d1;
  }

  // chain state: A=tgt0, B=dec0, C=tgt1, D=dec1 (frontier-live via SROA)
  Q qA[NJ], qB[NJ], qC[NJ], qD[NJ];
  Q gA[NJ], gB[NJ], gC[NJ], gD[NJ];
  V3 pA[NJ], pB[NJ], pC[NJ], pD[NJ];
  qA[0]=qB[0]=qC[0]=qD[0]=Q{1.f,0.f,0.f,0.f};
  gA[0]=gB[0]=gC[0]=gD[0]=Q{1.f,0.f,0.f,0.f};
  pA[0]=pB[0]=pC[0]=pD[0]=V3{0.f,0.f,0.f};

  static_for<NJ-1>([&](auto jc){
    constexpr int j = decltype(jc)::value + 1;      // 1..23
    float rA[4], rB[4], rC[4], rD[4];
    #pragma unroll
    for (int i = 0; i < 4; ++i) {
      const int c  = 4*j + i;
      const int oc = 8*j + i;
      rA[i] = tm0[oc*T_ + t];
      rB[i] = qs0[c*T_ + t];
      rC[i] = tm1[oc*T_ + t];
      rD[i] = qs1[c*T_ + t];
      float dB = rB[i] - rA[i];
      float dD = rD[i] - rC[i];
      accJ += dB*dB + dD*dD;
    }
    Q sA, sB, sC, sD;
    {
      const int c = 4*j;
      sA = Q{ rA[0]*s_std[c]+s_mean[c], rA[1]*s_std[c+1]+s_mean[c+1],
              rA[2]*s_std[c+2]+s_mean[c+2], rA[3]*s_std[c+3]+s_mean[c+3] };
      sB = Q{ rB[0]*s_std[c]+s_mean[c], rB[1]*s_std[c+1]+s_mean[c+1],
              rB[2]*s_std[c+2]+s_mean[c+2], rB[3]*s_std[c+3]+s_mean[c+3] };
      sC = Q{ rC[0]*s_std[c]+s_mean[c], rC[1]*s_std[c+1]+s_mean[c+1],
              rC[2]*s_std[c+2]+s_mean[c+2], rC[3]*s_std[c+3]+s_mean[c+3] };
      sD = Q{ rD[0]*s_std[c]+s_mean[c], rD[1]*s_std[c+1]+s_mean[c+1],
              rD[2]*s_std[c+2]+s_mean[c+2], rD[3]*s_std[c+3]+s_mean[c+3] };
    }
    stepChain<j>(qA, gA, pA, sA, s_off);
    stepChain<j>(qB, gB, pB, sB, s_off);
    stepChain<j>(qC, gC, pC, sC, s_off);
    stepChain<j>(qD, gD, pD, sD, s_off);

    float dx0 = pB[j].x - pA[j].x, dy0 = pB[j].y - pA[j].y, dz0 = pB[j].z - pA[j].z;
    float dx1 = pD[j].x - pC[j].x, dy1 = pD[j].y - pC[j].y, dz1 = pD[j].z - pC[j].z;
    fkAcc += dx0*dx0 + dy0*dy0 + dz0*dz0 + dx1*dx1 + dy1*dy1 + dz1*dz1;

    gw[(j*4+0)*T_ + t] = gB[j].w; gw[(j*4+1)*T_ + t] = gB[j].x;
    gw[(j*4+2)*T_ + t] = gB[j].y; gw[(j*4+3)*T_ + t] = gB[j].z;
    dw[(j*3+0)*T_ + t] = 2.f*(pB[j].x - pD[j].x);
    dw[(j*3+1)*T_ + t] = 2.f*(pB[j].y - pD[j].y);
    dw[(j*3+2)*T_ + t] = 2.f*(pB[j].z - pD[j].z);
  });

  float r  = waveSum(accR);
  float jj = waveSum(accJ);
  float fk = waveSum(fkAcc);
  const int wid = t >> 6;
  if ((t & 63) == 0) { sred[0][wid] = r; sred[1][wid] = jj; sred[2][wid] = fk; }
  __syncthreads();
  if (t == 0) {
    bpose[p]        = sred[0][0] + sred[0][1];
    bpose[512 + p]  = sred[1][0] + sred[1][1];
    bpose[1024 + p] = sred[2][0] + sred[2][1];
  }
}

// ---- Split path: bwd (grot/dgp from ws, write G) ----
__global__ __launch_bounds__(128) void k_pose_bwd(
    const float* __restrict__ qs,   const float* __restrict__ meanq,
    const float* __restrict__ stdq, const float* __restrict__ offs,
    const float* __restrict__ grot_ws, const float* __restrict__ dgp_ws,
    float* __restrict__ G)
{
  __shared__ float s_std[96], s_mean[96], s_off[72];
  const int p = blockIdx.x;
  const int t = threadIdx.x;
  if (t < 96) { s_std[t] = stdq[t]; s_mean[t] = meanq[t]; }
  if (t < 72) s_off[t] = offs[p*72 + t];
  __syncthreads();

  const float* qs0 = qs + (size_t)(2*p) * CT;
  const float* gw  = grot_ws + (size_t)p * (NJ*4*T_);
  const float* dw  = dgp_ws  + (size_t)p * (NJ*3*T_);
  float* Gp = G + (size_t)p * CT;

  float q[NJ][4];
  q[0][0]=1.f; q[0][1]=0.f; q[0][2]=0.f; q[0][3]=0.f;
  static_for<NJ-1>([&](auto jc){
    constexpr int j = decltype(jc)::value + 1;      // 1..23
    #pragma unroll
    for (int i = 0; i < 4; ++i) {
      const int c = 4*j + i;
      q[j][i] = qs0[c*T_ + t] * s_std[c] + s_mean[c];
    }
  });

  V3 dgpacc[NJ] = {};
  Q dgr[NJ] = {};
  Q dq [NJ] = {};
  static_for<NJ-1>([&](auto ic){
    constexpr int j = NJ - 1 - decltype(ic)::value;   // 23..1
    constexpr int P = PAR[j];
    V3 w{ dw[(j*3+0)*T_ + t] + dgpacc[j].x,
          dw[(j*3+1)*T_ + t] + dgpacc[j].y,
          dw[(j*3+2)*T_ + t] + dgpacc[j].z };
    Q gP;
    if constexpr (P == 0) gP = Q{1.f,0.f,0.f,0.f};
    else gP = Q{ gw[(P*4+0)*T_ + t], gw[(P*4+1)*T_ + t],
                 gw[(P*4+2)*T_ + t], gw[(P*4+3)*T_ + t] };
    if constexpr (P != 0) {
      dgpacc[P].x += w.x; dgpacc[P].y += w.y; dgpacc[P].z += w.z;
      V3 o{s_off[3*j], s_off[3*j+1], s_off[3*j+2]};
      dgr[P] = qadd(dgr[P], qrot_bwd_g(gP, o, w));
    }
    Q Gj = dgr[j];
    Q dL = qmul(qconj(gP), Gj);
    if constexpr (P != 0) {
      Q localj = qmul(qinv(loadQ<P>(q)), loadQ<j>(q));
      dgr[P] = qadd(dgr[P], qmul(Gj, qconj(localj)));
    }
    if constexpr (j < 4) {
      dq[j] = qadd(dq[j], dL);
    } else {
      Q qP  = loadQ<P>(q);
      Q iqP = qinv(qP);
      dq[j] = qadd(dq[j], qmul(qconj(iqP), dL));
      Q dInv = qmul(dL, qconj(loadQ<j>(q)));
      dq[P] = qadd(dq[P], qinv_bwd(qP, dInv));
    }
    Gp[(4*j+0)*T_ + t] = dq[j].w * s_std[4*j+0];
    Gp[(4*j+1)*T_ + t] = dq[j].x * s_std[4*j+1];
    Gp[(4*j+2)*T_ + t] = dq[j].y * s_std[4*j+2];
    Gp[(4*j+3)*T_ + t] = dq[j].z * s_std[4*j+3];
  });
  #pragma unroll
  for (int i = 0; i < 4; ++i) Gp[i*T_ + t] = 0.f;
}

// grad partials: part[s][p][z], SPLITK=16, K-chunk 768 (256 blocks)
__global__ __launch_bounds__(256) void k_gradgemm(
    const float* __restrict__ G, const float* __restrict__ W,
    float* __restrict__ part)
{
  __shared__ float As[64][33];
  __shared__ float Bs[128][33];
  const int tid = threadIdx.x;
  const int bn = blockIdx.x * 128;
  const int bm = blockIdx.y * 64;
  const int s  = blockIdx.z;
  const int kb = s * 768;
  float acc[4][8] = {};
  for (int k0 = 0; k0 < 768; k0 += 32) {
    #pragma unroll
    for (int r = 0; r < 2; ++r) {
      int idx = r*256 + tid;
      int row = idx >> 3;
      int kc  = (idx & 7) << 2;
      float4 v = *(const float4*)&G[(size_t)(bm + row)*CT + kb + k0 + kc];
      As[row][kc+0]=v.x; As[row][kc+1]=v.y; As[row][kc+2]=v.z; As[row][kc+3]=v.w;
    }
    #pragma unroll
    for (int r = 0; r < 4; ++r) {
      int idx = r*256 + tid;
      int row = idx >> 3;
      int kc  = (idx & 7) << 2;
      float4 v = *(const float4*)&W[(size_t)(bn + row)*CT + kb + k0 + kc];
      Bs[row][kc+0]=v.x; Bs[row][kc+1]=v.y; Bs[row][kc+2]=v.z; Bs[row][kc+3]=v.w;
    }
    __syncthreads();
    const int tx = tid & 15, ty = tid >> 4;
    #pragma unroll
    for (int kk = 0; kk < 32; ++kk) {
      float a[4], b[8];
      #pragma unroll
      for (int i = 0; i < 4; ++i) a[i] = As[ty*4+i][kk];
      #pragma unroll
      for (int j = 0; j < 8; ++j) b[j] = Bs[tx*8+j][kk];
      #pragma unroll
      for (int i = 0; i < 4; ++i)
        #pragma unroll
        for (int j = 0; j < 8; ++j) acc[i][j] += a[i]*b[j];
    }
    __syncthreads();
  }
  const int tx = tid & 15, ty = tid >> 4;
  #pragma unroll
  for (int i = 0; i < 4; ++i) {
    size_t pr = (size_t)s*131072 + (size_t)(bm + ty*4 + i)*256 + bn + tx*8;
    float4 o0{acc[i][0], acc[i][1], acc[i][2], acc[i][3]};
    float4 o1{acc[i][4], acc[i][5], acc[i][6], acc[i][7]};
    *(float4*)&part[pr]   = o0;
    *(float4*)&part[pr+4] = o1;
  }
}

// disp / kld / cons reductions — float4, block-partial, no atomics
__global__ __launch_bounds__(256) void k_rest(
    const float* __restrict__ ind, const float* __restrict__ tgd,
    const float* __restrict__ mu,  const float* __restrict__ lv,
    const float* __restrict__ lat, const float* __restrict__ part,
    float* __restrict__ brest)
{
  __shared__ float sred[3][4];
  const int t = threadIdx.x;
  const int gid = blockIdx.x * 256 + t;            // 0..131071
  float a0 = 0.f, a1 = 0.f, a2 = 0.f;
  if (gid < 98304) {
    float4 a = ((const float4*)ind)[gid];
    float4 b = ((const float4*)tgd)[gid];
    float dx=a.x-b.x, dy=a.y-b.y, dz=a.z-b.z, dw=a.w-b.w;
    a0 = dx*dx + dy*dy + dz*dz + dw*dw;
  }
  if (gid < 65536) {
    float4 l = ((const float4*)lv)[gid];
    float4 m = ((const float4*)mu)[gid];
    a1 = (1.f + l.x - m.x*m.x - __expf(l.x)) + (1.f + l.y - m.y*m.y - __expf(l.y))
       + (1.f + l.z - m.z*m.z - __expf(l.z)) + (1.f + l.w - m.w*m.w - __expf(l.w));
  }
  if (gid < 32768) {
    float4 g{0.f,0.f,0.f,0.f};
    #pragma unroll
    for (int s = 0; s < 16; ++s) {
      float4 v = ((const float4*)(part + (size_t)s*131072))[gid];
      g.x += v.x; g.y += v.y; g.z += v.z; g.w += v.w;
    }
    int p  = gid >> 6;
    int zb = (gid & 63) << 2;
    float4 La = *(const float4*)&lat[(size_t)(2*p)*ZDIM + zb];
    float4 Lb = *(const float4*)&lat[(size_t)(2*p+1)*ZDIM + zb];
    float vx = La.x - g.x - Lb.x, vy = La.y - g.y - Lb.y;
    float vz = La.z - g.z - Lb.z, vw = La.w - g.w - Lb.w;
    a2 = vx*vx + vy*vy + vz*vz + vw*vw;
  }
  a0 = waveSum(a0); a1 = waveSum(a1); a2 = waveSum(a2);
  const int wid = t >> 6;
  if ((t & 63) == 0) { sred[0][wid]=a0; sred[1][wid]=a1; sred[2][wid]=a2; }
  __syncthreads();
  if (t == 0) {
    brest[blockIdx.x]        = sred[0][0]+sred[0][1]+sred[0][2]+sred[0][3];
    brest[512 + blockIdx.x]  = sred[1][0]+sred[1][1]+sred[1][2]+sred[1][3];
    brest[1024 + blockIdx.x] = sred[2][0]+sred[2][1]+sred[2][2]+sred[2][3];
  }
}

__global__ __launch_bounds__(256) void k_final(
    const float* __restrict__ bpose, const float* __restrict__ brest,
    float* __restrict__ out)
{
  __shared__ float sred[4];
  const int t = threadIdx.x;
  float tot[6];
  const float* srcs[6] = { bpose, bpose+512, bpose+1024, brest, brest+512, brest+1024 };
  #pragma unroll
  for (int c = 0; c < 6; ++c) {
    float x = srcs[c][t] + srcs[c][t+256];
    x = waveSum(x);
    if ((t & 63) == 0) sred[t>>6] = x;
    __syncthreads();
    tot[c] = sred[0]+sred[1]+sred[2]+sred[3];
    __syncthreads();
  }
  if (t == 0) {
    out[0] = 0.001f * (-0.5f * tot[4] * (1.f/1024.f));       // kld
    out[1] = tot[0] * (1.f/524288.f);                        // root
    out[2] = tot[3] * (1.f/393216.f);                        // disp
    out[3] = 0.1f * (tot[5] * (1.f/131072.f));               // cons
    out[4] = 0.1f * (tot[2] * (1.f/9437184.f));              // fk
    out[5] = tot[1] * (1.f/12058624.f);                      // joints
  }
}

extern "C" void kernel_launch(void* const* d_in, const int* in_sizes, int n_in,
                              void* d_out, int out_size, void* d_ws, size_t ws_size,
                              hipStream_t stream)
{
  (void)in_sizes; (void)n_in; (void)out_size;
  const float* base = (const float*)d_in[0];
  const float* tmot = (const float*)d_in[1];
  const float* ind  = (const float*)d_in[2];
  const float* tgd  = (const float*)d_in[3];
  const float* mu   = (const float*)d_in[4];
  const float* lv   = (const float*)d_in[5];
  const float* lat  = (const float*)d_in[6];
  const float* W    = (const float*)d_in[7];
  const float* meanq= (const float*)d_in[8];
  const float* stdq = (const float*)d_in[9];
  const float* offs = (const float*)d_in[10];
  float* out = (float*)d_out;

  char* ws = (char*)d_ws;
  float* qs = (float*)(ws);                          // 50,331,648 B
  float* G  = (float*)(ws + 50331648);               // 25,165,824 B

  // split-mode extras (grot dead before part is produced -> part aliases grot)
  constexpr size_t OFF_GROT = 75497472;              // 25,165,824 B
  constexpr size_t OFF_PART_SPLIT = 75497472;        //  8,388,608 B (alias)
  constexpr size_t OFF_DGP  = 100663296;             // 18,874,368 B
  constexpr size_t OFF_BPOSE_SPLIT = 119537664;      // 6,144 B
  constexpr size_t OFF_BREST_SPLIT = 119543808;      // 6,144 B
  constexpr size_t WS_SPLIT_NEED   = 119549952;

  hipLaunchKernelGGL(k_decode, dim3(96, 8), dim3(256), 0, stream, base, lat, W, qs);

  if (ws_size >= WS_SPLIT_NEED) {
    float* grot  = (float*)(ws + OFF_GROT);
    float* dgp   = (float*)(ws + OFF_DGP);
    float* part  = (float*)(ws + OFF_PART_SPLIT);
    float* bpose = (float*)(ws + OFF_BPOSE_SPLIT);
    float* brest = (float*)(ws + OFF_BREST_SPLIT);
    hipLaunchKernelGGL(k_pose_fwd, dim3(512), dim3(128), 0, stream,
                       qs, tmot, meanq, stdq, offs, grot, dgp, bpose);
    hipLaunchKernelGGL(k_pose_bwd, dim3(512), dim3(128), 0, stream,
                       qs, meanq, stdq, offs, grot, dgp, G);
    hipLaunchKernelGGL(k_gradgemm, dim3(2, 8, 16), dim3(256), 0, stream, G, W, part);
    hipLaunchKernelGGL(k_rest, dim3(512), dim3(256), 0, stream,
                       ind, tgd, mu, lv, lat, part, brest);
    hipLaunchKernelGGL(k_final, dim3(1), dim3(256), 0, stream, bpose, brest, out);
  } else {
    float* part  = (float*)(ws + 75497472);          // 16*512*256*4 = 8,388,608
    float* bpose = (float*)(ws + 83886080);
    float* brest = (float*)(ws + 83892224);
    hipLaunchKernelGGL(k_pose, dim3(512), dim3(128), 0, stream,
                       qs, tmot, meanq, stdq, offs, G, bpose);
    hipLaunchKernelGGL(k_gradgemm, dim3(2, 8, 16), dim3(256), 0, stream, G, W, part);
    hipLaunchKernelGGL(k_rest, dim3(512), dim3(256), 0, stream,
                       ind, tgd, mu, lv, lat, part, brest);
    hipLaunchKernelGGL(k_final, dim3(1), dim3(256), 0, stream, bpose, brest, out);
  }
}